// Round 6
// baseline (133.401 us; speedup 1.0000x reference)
//
#include <hip/hip_runtime.h>
#include <math.h>

#define PI_F 3.14159265358979323846f

// ---------- complex helpers (float2 as complex) ----------
__device__ __forceinline__ float2 cmul2(float2 a, float2 b) {
    return make_float2(a.x * b.x - a.y * b.y, a.x * b.y + a.y * b.x);
}
// u*a + v*b
__device__ __forceinline__ float2 cmac2(float2 u, float2 a, float2 v, float2 b) {
    float2 r;
    r.x = u.x * a.x - u.y * a.y + v.x * b.x - v.y * b.y;
    r.y = u.x * a.y + u.y * a.x + v.x * b.y + v.y * b.x;
    return r;
}

struct M4 { float2 u00, u01, u10, u11; };

__device__ __forceinline__ M4 mmul4(const M4& A, const M4& B) {
    M4 R;
    R.u00 = cmac2(A.u00, B.u00, A.u01, B.u10);
    R.u01 = cmac2(A.u00, B.u01, A.u01, B.u11);
    R.u10 = cmac2(A.u10, B.u00, A.u11, B.u10);
    R.u11 = cmac2(A.u10, B.u01, A.u11, B.u11);
    return R;
}
__device__ __forceinline__ M4 mry(float t) {
    float c = cosf(0.5f * t), s = sinf(0.5f * t);
    M4 R; R.u00 = {c, 0}; R.u01 = {-s, 0}; R.u10 = {s, 0}; R.u11 = {c, 0};
    return R;
}
__device__ __forceinline__ M4 mrz(float t) {
    float c = cosf(0.5f * t), s = sinf(0.5f * t);
    M4 R; R.u00 = {c, -s}; R.u01 = {0, 0}; R.u10 = {0, 0}; R.u11 = {c, s};
    return R;
}
// Rot(phi, theta, omega) = RZ(omega) @ RY(theta) @ RZ(phi)
__device__ __forceinline__ M4 mrot(float phi, float th, float om) {
    return mmul4(mmul4(mrz(om), mry(th)), mrz(phi));
}

// fast tanh on the trans pipe: 1 - 2/(e^{2x}+1); exact to ~1e-6, saturates
// correctly at +-1 for |x| large.
__device__ __forceinline__ float fast_tanh(float x) {
    float e = __expf(2.f * x);
    return 1.f - 2.f / (e + 1.f);
}

// ---------- cross-lane xor-exchange ----------
// mask 1,2 -> DPP quad_perm (VALU)
// mask 8   -> DPP row_ror:8 (VALU): rotation by 8 within a 16-lane row is
//             exactly lane^8 and is direction-symmetric (no polarity risk).
// mask 4   -> ds_swizzle (rotation-by-4 != xor-4; keep the safe DS path)
// mask 16,32 -> v_permlane16/32_swap, both operands same register (verified R3)
__device__ __forceinline__ float plsw16(float v) {
    asm("v_permlane16_swap_b32 %0, %0" : "+v"(v));
    return v;
}
__device__ __forceinline__ float plsw32(float v) {
    asm("v_permlane32_swap_b32 %0, %0" : "+v"(v));
    return v;
}

template <int MASK>
__device__ __forceinline__ float lxor(float v) {
    if constexpr (MASK == 1)
        return __int_as_float(__builtin_amdgcn_update_dpp(
            0, __float_as_int(v), 0xB1, 0xF, 0xF, true));       // quad_perm [1,0,3,2]
    else if constexpr (MASK == 2)
        return __int_as_float(__builtin_amdgcn_update_dpp(
            0, __float_as_int(v), 0x4E, 0xF, 0xF, true));       // quad_perm [2,3,0,1]
    else if constexpr (MASK == 4)
        return __int_as_float(__builtin_amdgcn_ds_swizzle(__float_as_int(v), 0x101F));
    else if constexpr (MASK == 8)
        return __int_as_float(__builtin_amdgcn_update_dpp(
            0, __float_as_int(v), 0x128, 0xF, 0xF, true));      // row_ror:8 == lane^8
    else if constexpr (MASK == 16)
        return plsw16(v);
    else
        return plsw32(v);
}

template <int MASK>
__device__ __forceinline__ float2 lxor2(float2 v) {
    return make_float2(lxor<MASK>(v.x), lxor<MASK>(v.y));
}

template <int MASK>
__device__ __forceinline__ float rsum(float v) {
    return v + lxor<MASK>(v);
}

// broadcast lane L to all lanes as a wave-uniform scalar (SALU, no DS)
template <int L>
__device__ __forceinline__ float bcast(float v) {
    return __int_as_float(__builtin_amdgcn_readlane(__float_as_int(v), L));
}

// load an M4 from wave-uniform global memory (compiler emits scalar loads)
__device__ __forceinline__ M4 ldm(const float* __restrict__ g) {
    M4 M;
    M.u00 = make_float2(g[0], g[1]); M.u01 = make_float2(g[2], g[3]);
    M.u10 = make_float2(g[4], g[5]); M.u11 = make_float2(g[6], g[7]);
    return M;
}

// ---------- register statevector, 2 samples per wave: amp[q][r], q=sample ----------
// idx bit b: b in [0,2] -> register bit b; b in [3,8] -> lane bit (b-3).
// wire w -> idx bit (8-w). Wires 0..5 = lane bits 5..0; wires 6,7,8 = reg bits 2,1,0.

// single-qubit dense gate on register bit TB
template <int TB>
__device__ __forceinline__ void rot_reg(const M4& U, float2 (&amp)[2][8]) {
#pragma unroll
    for (int r = 0; r < 8; r++)
        if (((r >> TB) & 1) == 0) {
            int r1 = r | (1 << TB);
#pragma unroll
            for (int q = 0; q < 2; q++) {
                float2 a = amp[q][r], b = amp[q][r1];
                amp[q][r]  = cmac2(U.u00, a, U.u01, b);
                amp[q][r1] = cmac2(U.u10, a, U.u11, b);
            }
        }
}

// single-qubit dense gate on lane bit LB
template <int LB>
__device__ __forceinline__ void rot_lane(const M4& U, float2 (&amp)[2][8], int lane) {
    bool hi = (lane >> LB) & 1;
    float2 cA = hi ? U.u11 : U.u00;
    float2 cB = hi ? U.u10 : U.u01;
#pragma unroll
    for (int r = 0; r < 8; r++)
#pragma unroll
        for (int q = 0; q < 2; q++) {
            float2 o = lxor2<(1 << LB)>(amp[q][r]);
            amp[q][r] = cmac2(cA, amp[q][r], cB, o);
        }
}

template <int WIRE>
__device__ __forceinline__ void rot1(const M4& U, float2 (&amp)[2][8], int lane) {
    constexpr int BIT = 8 - WIRE;
    if constexpr (BIT < 3) rot_reg<BIT>(U, amp);
    else rot_lane<BIT - 3>(U, amp, lane);
}

// ---------- specialized controlled rotations (target = reg bit TB) ----------

// controlled RX: [[c, -i s], [-i s, c]]
template <int CBIT, int TB>
__device__ __forceinline__ void crx_g(float c, float s, float2 (&amp)[2][8], int lane) {
    if constexpr (CBIT >= 3) {
        bool ct = (lane >> (CBIT - 3)) & 1;
        float cc = ct ? c : 1.f, ss = ct ? s : 0.f;
#pragma unroll
        for (int r = 0; r < 8; r++)
            if (((r >> TB) & 1) == 0) {
                int r1 = r | (1 << TB);
#pragma unroll
                for (int q = 0; q < 2; q++) {
                    float2 a = amp[q][r], b = amp[q][r1];
                    amp[q][r]  = make_float2(cc * a.x + ss * b.y, cc * a.y - ss * b.x);
                    amp[q][r1] = make_float2(ss * a.y + cc * b.x, cc * b.y - ss * a.x);
                }
            }
    } else {
#pragma unroll
        for (int r = 0; r < 8; r++)
            if (((r >> CBIT) & 1) == 1 && ((r >> TB) & 1) == 0) {
                int r1 = r | (1 << TB);
#pragma unroll
                for (int q = 0; q < 2; q++) {
                    float2 a = amp[q][r], b = amp[q][r1];
                    amp[q][r]  = make_float2(c * a.x + s * b.y, c * a.y - s * b.x);
                    amp[q][r1] = make_float2(s * a.y + c * b.x, c * b.y - s * a.x);
                }
            }
    }
}

// controlled RY: [[c, -s], [s, c]] (real)
template <int CBIT, int TB>
__device__ __forceinline__ void cry_g(float c, float s, float2 (&amp)[2][8], int lane) {
    if constexpr (CBIT >= 3) {
        bool ct = (lane >> (CBIT - 3)) & 1;
        float cc = ct ? c : 1.f, ss = ct ? s : 0.f;
#pragma unroll
        for (int r = 0; r < 8; r++)
            if (((r >> TB) & 1) == 0) {
                int r1 = r | (1 << TB);
#pragma unroll
                for (int q = 0; q < 2; q++) {
                    float2 a = amp[q][r], b = amp[q][r1];
                    amp[q][r]  = make_float2(cc * a.x - ss * b.x, cc * a.y - ss * b.y);
                    amp[q][r1] = make_float2(ss * a.x + cc * b.x, ss * a.y + cc * b.y);
                }
            }
    } else {
#pragma unroll
        for (int r = 0; r < 8; r++)
            if (((r >> CBIT) & 1) == 1 && ((r >> TB) & 1) == 0) {
                int r1 = r | (1 << TB);
#pragma unroll
                for (int q = 0; q < 2; q++) {
                    float2 a = amp[q][r], b = amp[q][r1];
                    amp[q][r]  = make_float2(c * a.x - s * b.x, c * a.y - s * b.y);
                    amp[q][r1] = make_float2(s * a.x + c * b.x, s * a.y + c * b.y);
                }
            }
    }
}

// controlled RZ: diag(e, conj(e)), e = c - i s
template <int CBIT, int TB>
__device__ __forceinline__ void crz_g(float c, float s, float2 (&amp)[2][8], int lane) {
    if constexpr (CBIT >= 3) {
        bool ct = (lane >> (CBIT - 3)) & 1;
        float cc = ct ? c : 1.f, ss = ct ? s : 0.f;
#pragma unroll
        for (int r = 0; r < 8; r++)
            if (((r >> TB) & 1) == 0) {
                int r1 = r | (1 << TB);
#pragma unroll
                for (int q = 0; q < 2; q++) {
                    float2 a = amp[q][r], b = amp[q][r1];
                    amp[q][r]  = make_float2(cc * a.x + ss * a.y, cc * a.y - ss * a.x);
                    amp[q][r1] = make_float2(cc * b.x - ss * b.y, cc * b.y + ss * b.x);
                }
            }
    } else {
#pragma unroll
        for (int r = 0; r < 8; r++)
            if (((r >> CBIT) & 1) == 1 && ((r >> TB) & 1) == 0) {
                int r1 = r | (1 << TB);
#pragma unroll
                for (int q = 0; q < 2; q++) {
                    float2 a = amp[q][r], b = amp[q][r1];
                    amp[q][r]  = make_float2(c * a.x + s * a.y, c * a.y - s * a.x);
                    amp[q][r1] = make_float2(c * b.x - s * b.y, c * b.y + s * b.x);
                }
            }
    }
}

template <int CW, int TW>
__device__ __forceinline__ void cnotg(float2 (&amp)[2][8], int lane) {
    constexpr int CBIT = 8 - CW, TBIT = 8 - TW;
    if constexpr (CBIT < 3 && TBIT < 3) {
#pragma unroll
        for (int r = 0; r < 8; r++)
            if (((r >> CBIT) & 1) == 1 && ((r >> TBIT) & 1) == 0) {
                int r1 = r | (1 << TBIT);
#pragma unroll
                for (int q = 0; q < 2; q++) {
                    float2 t = amp[q][r]; amp[q][r] = amp[q][r1]; amp[q][r1] = t;
                }
            }
    } else if constexpr (CBIT >= 3 && TBIT < 3) {
        bool c = (lane >> (CBIT - 3)) & 1;
#pragma unroll
        for (int r = 0; r < 8; r++)
            if (((r >> TBIT) & 1) == 0) {
                int r1 = r | (1 << TBIT);
#pragma unroll
                for (int q = 0; q < 2; q++) {
                    float2 t0 = amp[q][r], t1 = amp[q][r1];
                    amp[q][r]  = c ? t1 : t0;
                    amp[q][r1] = c ? t0 : t1;
                }
            }
    } else if constexpr (CBIT < 3 && TBIT >= 3) {
#pragma unroll
        for (int r = 0; r < 8; r++)
            if (((r >> CBIT) & 1) == 1)
#pragma unroll
                for (int q = 0; q < 2; q++)
                    amp[q][r] = lxor2<(1 << (TBIT - 3))>(amp[q][r]);
    } else {
        bool c = (lane >> (CBIT - 3)) & 1;
#pragma unroll
        for (int r = 0; r < 8; r++)
#pragma unroll
            for (int q = 0; q < 2; q++) {
                float2 o = lxor2<(1 << (TBIT - 3))>(amp[q][r]);
                amp[q][r] = c ? o : amp[q][r];
            }
    }
}

// StronglyEntanglingLayers, L=1, 3 wires; matrices hoisted to registers by caller
template <int W0, int W1, int W2>
__device__ __forceinline__ void sel3m(const M4& A, const M4& B, const M4& C,
                                      float2 (&amp)[2][8], int lane) {
    rot1<W0>(A, amp, lane);
    rot1<W1>(B, amp, lane);
    rot1<W2>(C, amp, lane);
    cnotg<W0, W1>(amp, lane);
    cnotg<W1, W2>(amp, lane);
    cnotg<W2, W0>(amp, lane);
}

template <int I>
__device__ __forceinline__ void block_i(float2 (&amp)[2][8], float cx, float sx, float cy1, float sy1,
                                        float cz, float sz, float cy2, float sy2,
                                        const M4& S0a, const M4& S0b, const M4& S0c,
                                        const M4& S1a, const M4& S1b, const M4& S1c, int lane) {
    crx_g<4 - I, 1>(cx,  sx,  amp, lane);
    cry_g<8 - I, 1>(cy1, sy1, amp, lane);
    crz_g<4 - I, 0>(cz,  sz,  amp, lane);
    cry_g<8 - I, 0>(cy2, sy2, amp, lane);
    sel3m<I, 4 + I, 7>(S0a, S0b, S0c, amp, lane);   // strong[0]
    sel3m<7, 4 + I, 8>(S1a, S1b, S1c, amp, lane);   // strong[1]
}

// ---------- kernel A': tiny prep (gate table + zero gsum/gcnt) ----------
__global__ void prep_kernel(const float* __restrict__ strong, const float* __restrict__ inits,
                            const float* __restrict__ update,
                            float* __restrict__ gm, float* __restrict__ zbuf, int nzero) {
    int j = threadIdx.x;
    if (j < 4) {
        gm[2 * j]     = cosf(0.5f * inits[j]);
        gm[2 * j + 1] = sinf(0.5f * inits[j]);
    } else if (j < 13) {
        const float* w;
        if (j < 7)       w = strong + (j - 4) * 3;
        else if (j < 10) w = strong + 9 + (j - 7) * 3;
        else             w = update + (j - 10) * 3;
        M4 M = mrot(w[0], w[1], w[2]);
        float* o = gm + 8 + (j - 4) * 8;
        o[0] = M.u00.x; o[1] = M.u00.y; o[2] = M.u01.x; o[3] = M.u01.y;
        o[4] = M.u10.x; o[5] = M.u10.y; o[6] = M.u11.x; o[7] = M.u11.y;
    }
    for (int i = j; i < nzero; i += 64) zbuf[i] = 0.f;
}

// ---------- kernel B: fused feature-MLPs + PQC + update-MLP + pooling ----------
// TWO samples per wave; gate table hoisted; broadcasts via readlane (no DS);
// mask-8 exchanges via DPP row_ror:8 (no DS).
#define MAX_GRAPHS 64
__global__ __launch_bounds__(256, 2) void pqc_fused_kernel(
        const float* __restrict__ node_feat, const float* __restrict__ edge_attr,
        const float* __restrict__ Wn1, const float* __restrict__ bn1,
        const float* __restrict__ Wn2, const float* __restrict__ bn2,
        const float* __restrict__ We1, const float* __restrict__ be1,
        const float* __restrict__ We2, const float* __restrict__ be2,
        const int* __restrict__ subgraphs, const int* __restrict__ edge_ids,
        const int* __restrict__ batch, const float* __restrict__ gm,
        const float* __restrict__ Wu1, const float* __restrict__ bu1,
        const float* __restrict__ Wu2, const float* __restrict__ bu2,
        float* __restrict__ gsum, float* __restrict__ gcnt,
        int ntot, int ngraphs) {
    __shared__ float bins[3 * MAX_GRAPHS];
    for (int i = threadIdx.x; i < 3 * ngraphs; i += 256) bins[i] = 0.f;
    __syncthreads();

    int wave = threadIdx.x >> 6;
    int lane = threadIdx.x & 63;
    int s0 = (blockIdx.x * 4 + wave) * 2;

    if (s0 < ntot) {
        int j1 = lane, j2 = lane + 64;
        bool ok1 = (s0 + 1) < ntot;
        int sq[2] = {s0, ok1 ? s0 + 1 : s0};

        // ---- gate table: hoisted; latency hides under the MLP phase ----
        float cx  = gm[0], sx  = gm[1];
        float cy1 = gm[2], sy1 = gm[3];
        float cz  = gm[4], sz  = gm[5];
        float cy2 = gm[6], sy2 = gm[7];
        M4 S0a = ldm(gm + 8),  S0b = ldm(gm + 16), S0c = ldm(gm + 24);
        M4 S1a = ldm(gm + 32), S1b = ldm(gm + 40), S1c = ldm(gm + 48);
        M4 Upa = ldm(gm + 56), Upb = ldm(gm + 64), Upc = ldm(gm + 72);

        // ---- per-lane weight preloads (L2-hot, shared by both samples) ----
        float wn1a[8], wn1b[8];
#pragma unroll
        for (int k = 0; k < 8; k++) { wn1a[k] = Wn1[k * 128 + j1]; wn1b[k] = Wn1[k * 128 + j2]; }
        float bn1a = bn1[j1], bn1b = bn1[j2];
        float wn2a0 = Wn2[2 * j1], wn2a1 = Wn2[2 * j1 + 1];
        float wn2b0 = Wn2[2 * j2], wn2b1 = Wn2[2 * j2 + 1];
        float we1a[4], we1b[4];
#pragma unroll
        for (int k = 0; k < 4; k++) { we1a[k] = We1[k * 128 + j1]; we1b[k] = We1[k * 128 + j2]; }
        float be1a = be1[j1], be1b = be1[j2];
        float we2a0 = We2[2 * j1], we2a1 = We2[2 * j1 + 1];
        float we2b0 = We2[2 * j2], we2b1 = We2[2 * j2 + 1];

        // ---- sample indices ----
        int cidx[2];
        int nid[2][4];
        int eid[2][3];
#pragma unroll
        for (int q = 0; q < 2; q++) {
            const int4 sg = *reinterpret_cast<const int4*>(subgraphs + (size_t)sq[q] * 4);
            cidx[q] = sg.x;
            nid[q][0] = sg.x; nid[q][1] = sg.y; nid[q][2] = sg.z; nid[q][3] = sg.w;
#pragma unroll
            for (int j = 0; j < 3; j++) eid[q][j] = edge_ids[sq[q] * 3 + j];
        }

        // ---- feature MLP partials: value idx 2r+ch, rows 0..2 edges, 3..6 nodes ----
        float o0a[2][7], o1a[2][7];
#pragma unroll
        for (int q = 0; q < 2; q++) {
#pragma unroll
            for (int j = 0; j < 3; j++) {
                const float4 f = *reinterpret_cast<const float4*>(edge_attr + (size_t)eid[q][j] * 4);
                float h1 = be1a + f.x * we1a[0] + f.y * we1a[1] + f.z * we1a[2] + f.w * we1a[3];
                float h2 = be1b + f.x * we1b[0] + f.y * we1b[1] + f.z * we1b[2] + f.w * we1b[3];
                h1 = h1 > 0.f ? h1 : 0.01f * h1;
                h2 = h2 > 0.f ? h2 : 0.01f * h2;
                o0a[q][j] = h1 * we2a0 + h2 * we2b0;
                o1a[q][j] = h1 * we2a1 + h2 * we2b1;
            }
#pragma unroll
            for (int j = 0; j < 4; j++) {
                const float4* nf = reinterpret_cast<const float4*>(node_feat + (size_t)nid[q][j] * 8);
                const float4 fa = nf[0], fb = nf[1];
                float h1 = bn1a + fa.x * wn1a[0] + fa.y * wn1a[1] + fa.z * wn1a[2] + fa.w * wn1a[3]
                                + fb.x * wn1a[4] + fb.y * wn1a[5] + fb.z * wn1a[6] + fb.w * wn1a[7];
                float h2 = bn1b + fa.x * wn1b[0] + fa.y * wn1b[1] + fa.z * wn1b[2] + fa.w * wn1b[3]
                                + fb.x * wn1b[4] + fb.y * wn1b[5] + fb.z * wn1b[6] + fb.w * wn1b[7];
                h1 = h1 > 0.f ? h1 : 0.01f * h1;
                h2 = h2 > 0.f ? h2 : 0.01f * h2;
                o0a[q][3 + j] = h1 * wn2a0 + h2 * wn2b0;
                o1a[q][3 + j] = h1 * wn2a1 + h2 * wn2b1;
            }
        }

        // ---- value-packing fold (both samples interleaved): lane j holds value j ----
        float L1[2][7];
#pragma unroll
        for (int i = 0; i < 7; i++)
#pragma unroll
            for (int q = 0; q < 2; q++) {
                float r0 = rsum<1>(o0a[q][i]);
                float r1 = rsum<1>(o1a[q][i]);
                L1[q][i] = (lane & 1) ? r1 : r0;
            }
        float L2[2][4];
#pragma unroll
        for (int i = 0; i < 3; i++)
#pragma unroll
            for (int q = 0; q < 2; q++) {
                float r0 = rsum<2>(L1[q][2 * i]);
                float r1 = rsum<2>(L1[q][2 * i + 1]);
                L2[q][i] = (lane & 2) ? r1 : r0;
            }
#pragma unroll
        for (int q = 0; q < 2; q++) L2[q][3] = rsum<2>(L1[q][6]);
        float L3[2][2];
#pragma unroll
        for (int i = 0; i < 2; i++)
#pragma unroll
            for (int q = 0; q < 2; q++) {
                float r0 = rsum<4>(L2[q][2 * i]);
                float r1 = rsum<4>(L2[q][2 * i + 1]);
                L3[q][i] = (lane & 4) ? r1 : r0;
            }
        float T[2];
#pragma unroll
        for (int q = 0; q < 2; q++) {
            float r0 = rsum<8>(L3[q][0]);
            float r1 = rsum<8>(L3[q][1]);
            T[q] = (lane & 8) ? r1 : r0;
            T[q] = rsum<16>(T[q]);
            T[q] = rsum<32>(T[q]);
        }

        // ---- tanh + half-angle trig on designated lanes (0..13) ----
        float be2_0 = be2[0], be2_1 = be2[1];
        float bn2_0 = bn2[0], bn2_1 = bn2[1];
        float bias = (lane < 6) ? ((lane & 1) ? be2_1 : be2_0)
                                : ((lane & 1) ? bn2_1 : bn2_0);
        float t[2], ca[2], sa[2];
#pragma unroll
        for (int q = 0; q < 2; q++) {
            t[q]  = fast_tanh(T[q] + bias) * PI_F;   // valid on lanes 0..13
            float ah = 0.5f * t[q];
            ca[q] = __cosf(ah);
            sa[q] = __sinf(ah);
        }
        float f0[2], f1[2];
#pragma unroll
        for (int q = 0; q < 2; q++) {
            f0[q] = bcast<6>(t[q]);    // ang[3][0] = x[cidx].0 (uniform)
            f1[q] = bcast<7>(t[q]);    // ang[3][1] = x[cidx].1 (uniform)
        }

        // ---- encoding layer on |0..0>: product state; readlane broadcasts ----
        float2 cacc[2] = {make_float2(1.f, 0.f), make_float2(1.f, 0.f)};
#pragma unroll
        for (int q = 0; q < 2; q++) {
            // wire 0 (lane bit 5)
            {
                float c0 = bcast<0>(ca[q]), s0 = bcast<0>(sa[q]);
                float c1 = bcast<1>(ca[q]), s1 = bcast<1>(sa[q]);
                int bit = (lane >> 5) & 1;
                float2 v0 = make_float2(c0 * c1, -c0 * s1);
                float2 v1 = make_float2(s0 * c1,  s0 * s1);
                cacc[q] = bit ? v1 : v0;     // first factor: no multiply needed
            }
            {
                float c0 = bcast<2>(ca[q]), s0 = bcast<2>(sa[q]);
                float c1 = bcast<3>(ca[q]), s1 = bcast<3>(sa[q]);
                int bit = (lane >> 4) & 1;
                float2 v0 = make_float2(c0 * c1, -c0 * s1);
                float2 v1 = make_float2(s0 * c1,  s0 * s1);
                cacc[q] = cmul2(cacc[q], bit ? v1 : v0);
            }
            {
                float c0 = bcast<4>(ca[q]), s0 = bcast<4>(sa[q]);
                float c1 = bcast<5>(ca[q]), s1 = bcast<5>(sa[q]);
                int bit = (lane >> 3) & 1;
                float2 v0 = make_float2(c0 * c1, -c0 * s1);
                float2 v1 = make_float2(s0 * c1,  s0 * s1);
                cacc[q] = cmul2(cacc[q], bit ? v1 : v0);
            }
            {
                float c0 = bcast<6>(ca[q]), s0 = bcast<6>(sa[q]);
                float c1 = bcast<7>(ca[q]), s1 = bcast<7>(sa[q]);
                int bit = (lane >> 2) & 1;
                float2 v0 = make_float2(c0 * c1, -c0 * s1);
                float2 v1 = make_float2(s0 * c1,  s0 * s1);
                cacc[q] = cmul2(cacc[q], bit ? v1 : v0);
            }
            {
                float c0 = bcast<8>(ca[q]), s0 = bcast<8>(sa[q]);
                float c1 = bcast<9>(ca[q]), s1 = bcast<9>(sa[q]);
                int bit = (lane >> 1) & 1;
                float2 v0 = make_float2(c0 * c1, -c0 * s1);
                float2 v1 = make_float2(s0 * c1,  s0 * s1);
                cacc[q] = cmul2(cacc[q], bit ? v1 : v0);
            }
            {
                float c0 = bcast<10>(ca[q]), s0 = bcast<10>(sa[q]);
                float c1 = bcast<11>(ca[q]), s1 = bcast<11>(sa[q]);
                int bit = lane & 1;
                float2 v0 = make_float2(c0 * c1, -c0 * s1);
                float2 v1 = make_float2(s0 * c1,  s0 * s1);
                cacc[q] = cmul2(cacc[q], bit ? v1 : v0);
            }
        }
        float2 amp[2][8];
#pragma unroll
        for (int q = 0; q < 2; q++) {
#pragma unroll
            for (int r = 0; r < 8; r++) amp[q][r] = make_float2(0.f, 0.f);
            float c6 = bcast<12>(ca[q]), s6 = bcast<12>(sa[q]);
            float c7 = bcast<13>(ca[q]), s7 = bcast<13>(sa[q]);
            amp[q][0] = cmul2(cacc[q], make_float2(c6 * c7, -c6 * s7));
            amp[q][4] = cmul2(cacc[q], make_float2(s6 * c7,  s6 * s7));
        }

        // ---- PQC (both samples interleaved inside every gate) ----
        block_i<0>(amp, cx, sx, cy1, sy1, cz, sz, cy2, sy2, S0a, S0b, S0c, S1a, S1b, S1c, lane);
        block_i<1>(amp, cx, sx, cy1, sy1, cz, sz, cy2, sy2, S0a, S0b, S0c, S1a, S1b, S1c, lane);
        block_i<2>(amp, cx, sx, cy1, sy1, cz, sz, cy2, sy2, S0a, S0b, S0c, S1a, S1b, S1c, lane);
        sel3m<3, 7, 8>(Upa, Upb, Upc, amp, lane);

        // <X_3>: pair product (mask 4) then butterfly
        float acc[2] = {0.f, 0.f};
#pragma unroll
        for (int r = 0; r < 8; r++)
#pragma unroll
            for (int q = 0; q < 2; q++) {
                float2 o = lxor2<4>(amp[q][r]);
                acc[q] += amp[q][r].x * o.x + amp[q][r].y * o.y;
            }
#pragma unroll
        for (int q = 0; q < 2; q++) {
            acc[q] = rsum<1>(acc[q]);
            acc[q] = rsum<2>(acc[q]);
            acc[q] = rsum<4>(acc[q]);
            acc[q] = rsum<8>(acc[q]);
            acc[q] = rsum<16>(acc[q]);
            acc[q] = rsum<32>(acc[q]);
        }

        // ---- update MLP [f0,f1,acc] -> 128 -> 2, wave-parallel, both samples ----
        float wu1a0 = Wu1[j1], wu1a1 = Wu1[128 + j1], wu1a2 = Wu1[256 + j1], bu1a = bu1[j1];
        float wu1b0 = Wu1[j2], wu1b1 = Wu1[128 + j2], wu1b2 = Wu1[256 + j2], bu1b = bu1[j2];
        float wu2a0 = Wu2[2 * j1], wu2a1 = Wu2[2 * j1 + 1];
        float wu2b0 = Wu2[2 * j2], wu2b1 = Wu2[2 * j2 + 1];
        float o0[2], o1[2];
#pragma unroll
        for (int q = 0; q < 2; q++) {
            float h1 = bu1a + f0[q] * wu1a0 + f1[q] * wu1a1 + acc[q] * wu1a2;
            float h2 = bu1b + f0[q] * wu1b0 + f1[q] * wu1b1 + acc[q] * wu1b2;
            h1 = h1 > 0.f ? h1 : 0.01f * h1;
            h2 = h2 > 0.f ? h2 : 0.01f * h2;
            o0[q] = h1 * wu2a0 + h2 * wu2b0;
            o1[q] = h1 * wu2a1 + h2 * wu2b1;
        }
#pragma unroll
        for (int q = 0; q < 2; q++) {
            o0[q] = rsum<1>(o0[q]);  o1[q] = rsum<1>(o1[q]);
            o0[q] = rsum<2>(o0[q]);  o1[q] = rsum<2>(o1[q]);
            o0[q] = rsum<4>(o0[q]);  o1[q] = rsum<4>(o1[q]);
            o0[q] = rsum<8>(o0[q]);  o1[q] = rsum<8>(o1[q]);
            o0[q] = rsum<16>(o0[q]); o1[q] = rsum<16>(o1[q]);
            o0[q] = rsum<32>(o0[q]); o1[q] = rsum<32>(o1[q]);
        }

        // ---- pooling: x[s] (pre-update) + scattered update ----
        float xs0[2], xs1[2];
#pragma unroll
        for (int q = 0; q < 2; q++) { xs0[q] = f0[q]; xs1[q] = f1[q]; }
#pragma unroll
        for (int q = 0; q < 2; q++)
            if (cidx[q] != sq[q]) {
                // generic fallback (cold; never taken for this input layout)
                const float4* nf = reinterpret_cast<const float4*>(node_feat + (size_t)sq[q] * 8);
                const float4 fa = nf[0], fb = nf[1];
                float g1 = bn1a, g2 = bn1b;
                const float fv[8] = {fa.x, fa.y, fa.z, fa.w, fb.x, fb.y, fb.z, fb.w};
#pragma unroll
                for (int k = 0; k < 8; k++) {
                    g1 += fv[k] * wn1a[k];
                    g2 += fv[k] * wn1b[k];
                }
                g1 = g1 > 0.f ? g1 : 0.01f * g1;
                g2 = g2 > 0.f ? g2 : 0.01f * g2;
                float p0 = g1 * wn2a0 + g2 * wn2b0;
                float p1 = g1 * wn2a1 + g2 * wn2b1;
                for (int off = 32; off > 0; off >>= 1) {
                    p0 += __shfl_xor(p0, off, 64);
                    p1 += __shfl_xor(p1, off, 64);
                }
                xs0[q] = tanhf(p0 + bn2_0) * PI_F;
                xs1[q] = tanhf(p1 + bn2_1) * PI_F;
            }

        if (lane == 0) {
#pragma unroll
            for (int q = 0; q < 2; q++) {
                if (q == 1 && !ok1) break;
                float u0 = o0[q] + bu2[0], u1 = o1[q] + bu2[1];
                int bs = batch[sq[q]], bc = batch[cidx[q]];
                atomicAdd(&bins[3 * bs + 0], xs0[q]);
                atomicAdd(&bins[3 * bs + 1], xs1[q]);
                atomicAdd(&bins[3 * bs + 2], 1.f);
                atomicAdd(&bins[3 * bc + 0], u0);
                atomicAdd(&bins[3 * bc + 1], u1);
            }
        }
    }
    __syncthreads();

    // flush non-zero bins (typically 1 graph per block)
    for (int i = threadIdx.x; i < ngraphs; i += 256) {
        float a0 = bins[3 * i + 0], a1 = bins[3 * i + 1], ac = bins[3 * i + 2];
        if (a0 != 0.f || a1 != 0.f || ac != 0.f) {
            atomicAdd(&gsum[2 * i + 0], a0);
            atomicAdd(&gsum[2 * i + 1], a1);
            atomicAdd(&gcnt[i], ac);
        }
    }
}

// ---------- kernel C: g = gsum/gcnt; out = mlp(g, 2->2->2) ----------
__global__ void head_kernel(const float* __restrict__ gsum, const float* __restrict__ gcnt,
                            const float* __restrict__ Wh1, const float* __restrict__ bh1,
                            const float* __restrict__ Wh2, const float* __restrict__ bh2,
                            float* __restrict__ out, int ngraphs) {
    int g = threadIdx.x;
    if (g >= ngraphs) return;
    float c = gcnt[g];
    float g0 = gsum[2 * g + 0] / c;
    float g1 = gsum[2 * g + 1] / c;
    float h0 = g0 * Wh1[0] + g1 * Wh1[2] + bh1[0];
    float h1 = g0 * Wh1[1] + g1 * Wh1[3] + bh1[1];
    h0 = h0 > 0.f ? h0 : 0.01f * h0;
    h1 = h1 > 0.f ? h1 : 0.01f * h1;
    out[2 * g + 0] = h0 * Wh2[0] + h1 * Wh2[2] + bh2[0];
    out[2 * g + 1] = h0 * Wh2[1] + h1 * Wh2[3] + bh2[1];
}

extern "C" void kernel_launch(void* const* d_in, const int* in_sizes, int n_in,
                              void* d_out, int out_size, void* d_ws, size_t ws_size,
                              hipStream_t stream) {
    const float* node_feat = (const float*)d_in[0];   // (N, 8)
    const float* edge_attr = (const float*)d_in[1];   // (3N, 4)
    const float* Wn1 = (const float*)d_in[2];
    const float* bn1 = (const float*)d_in[3];
    const float* Wn2 = (const float*)d_in[4];
    const float* bn2 = (const float*)d_in[5];
    const float* We1 = (const float*)d_in[6];
    const float* be1 = (const float*)d_in[7];
    const float* We2 = (const float*)d_in[8];
    const float* be2 = (const float*)d_in[9];
    const float* strong = (const float*)d_in[10];     // (2,1,3,3)
    const float* inits  = (const float*)d_in[11];     // (1,4)
    const float* update = (const float*)d_in[12];     // (1,3,3)
    const float* Wu1 = (const float*)d_in[13];
    const float* bu1 = (const float*)d_in[14];
    const float* Wu2 = (const float*)d_in[15];
    const float* bu2 = (const float*)d_in[16];
    const float* Wh1 = (const float*)d_in[17];
    const float* bh1 = (const float*)d_in[18];
    const float* Wh2 = (const float*)d_in[19];
    const float* bh2 = (const float*)d_in[20];
    const int* subgraphs = (const int*)d_in[21];      // (N, 4)
    const int* edge_ids  = (const int*)d_in[22];      // (N, 3)
    const int* batch     = (const int*)d_in[23];      // (N,)

    const int N  = in_sizes[0] / 8;      // 4096 nodes (= samples)
    const int NG = out_size / 2;         // 16 graphs

    // workspace layout (floats)
    float* ws   = (float*)d_ws;
    float* gsum = ws;                    // NG*2
    float* gcnt = gsum + (size_t)NG * 2; // NG       (contiguous with gsum)
    float* gm   = gcnt + NG;             // 80 floats of gate data

    // Kernel A': gate table + zero gsum/gcnt (1 block)
    prep_kernel<<<1, 64, 0, stream>>>(strong, inits, update, gm, gsum, 3 * NG);

    // Kernel B: fused feature-MLPs + PQC + update MLP + pooling (2 samples/wave)
    pqc_fused_kernel<<<(N + 7) / 8, 256, 0, stream>>>(
        node_feat, edge_attr, Wn1, bn1, Wn2, bn2, We1, be1, We2, be2,
        subgraphs, edge_ids, batch, gm, Wu1, bu1, Wu2, bu2,
        gsum, gcnt, N, NG);

    // Kernel C: head
    head_kernel<<<1, 64, 0, stream>>>(gsum, gcnt, Wh1, bh1, Wh2, bh2, (float*)d_out, NG);
}